// Round 1
// baseline (1572.493 us; speedup 1.0000x reference)
//
#include <hip/hip_runtime.h>

// cost volume: out[n,h,w,9*dh+dw] = (1/128) * sum_c f1[n,h,w,c]*f2[n,h+dh-4,w+dw-4,c]
// N=8 H=128 W=256 C=128, zero-padded f2 borders.

#define NN 8
#define HH 128
#define WW 256
#define CC 128

constexpr int WT   = 128;   // w-tile per workgroup
constexpr int P    = 8;     // pixels per group (register tile)
constexpr int S    = 16;    // c-split slots
constexpr int KC   = 16;    // c per staged block
constexpr int NCB  = CC / KC;         // 8
constexpr int F2ST = 140;             // staged row stride (floats), mult of 4, 140%32=12 spreads banks
constexpr int STG  = F2ST * KC;       // 2240 floats per staging buffer (x2 = double buffer)
constexpr int RST  = 260;             // reduction row stride; 260%32=4 spreads reduce-read banks
constexpr int LDSF = 36 * RST;        // 9360 floats = 36.6 KB (> 2*STG=4480 staging floats)

__global__ __launch_bounds__(256, 3)
void cost_volume_kernel(const float* __restrict__ f1,
                        const float* __restrict__ f2,
                        float* __restrict__ out) {
    __shared__ __align__(16) float lds[LDSF];

    const int t  = threadIdx.x;
    const int g  = t >> 4;      // 0..15 pixel-group
    const int s  = t & 15;      // 0..15 c-slot
    const int p0 = g * P;       // local pixel base 0..120

    // block swizzle: give each XCD (b&7) a contiguous 16-row h-chunk for f2 L2 reuse
    int b   = blockIdx.x;
    int xcd = b & 7;
    int i   = b >> 3;            // 0..255
    int wt  = i & 1;
    int h   = (xcd << 4) | ((i >> 1) & 15);
    int n   = i >> 5;            // 0..7
    const int w0 = wt * WT;

    const float* f1row = f1 + (((long)(n * HH) + h) * WW + w0) * CC;

    // ---- hoist f1 into registers ONCE (was re-read from HBM for each of 9 dh) ----
    // fa_all[cb*8+k] = f1[w0+p0+k][cb*16+s]
    float fa_all[64];
    #pragma unroll
    for (int cb = 0; cb < NCB; ++cb) {
        #pragma unroll
        for (int k = 0; k < P; ++k)
            fa_all[cb * 8 + k] = f1row[(p0 + k) * CC + cb * KC + s];
    }

    for (int dh = 0; dh < 9; ++dh) {
        const int y = h + dh - 4;
        const bool valid = (y >= 0 && y < HH);   // workgroup-uniform

        float acc[72];
        #pragma unroll
        for (int a = 0; a < 72; ++a) acc[a] = 0.f;

        if (valid) {
            const float* f2row = f2 + (((long)(n * HH) + y) * WW) * CC;

            // stage f2T[cc][x+4] for c-block cb into staging buffer buf (0/1)
            // via 4x4 register transpose blocks; 34 x-blocks * 4 c-quads = 136 tasks
            auto stage = [&](int buf, int cb) {
                const int c0 = cb * KC;
                const int c4 = t & 3;
                const int xb = t >> 2;          // 0..33
                const int x0 = xb * 4 - 4;      // local x base, covers x0..x0+3
                float* dst = &lds[buf * STG];
                float4 v[4];
                #pragma unroll
                for (int ii = 0; ii < 4; ++ii) {
                    const int xg = w0 + x0 + ii;
                    if (xg >= 0 && xg < WW) {
                        v[ii] = *(const float4*)(f2row + (long)xg * CC + c0 + c4 * 4);
                    } else {
                        v[ii] = make_float4(0.f, 0.f, 0.f, 0.f);
                    }
                }
                #pragma unroll
                for (int j = 0; j < 4; ++j) {
                    float4 w4;
                    w4.x = ((const float*)&v[0])[j];
                    w4.y = ((const float*)&v[1])[j];
                    w4.z = ((const float*)&v[2])[j];
                    w4.w = ((const float*)&v[3])[j];
                    *(float4*)&dst[(c4 * 4 + j) * F2ST + (x0 + 4)] = w4;
                }
            };

            // prologue: previous dh's reduction reads must finish before we overwrite lds
            __syncthreads();
            if (t < 136) stage(0, 0);

            // double-buffered c-block loop: ONE barrier per cb, staging of cb+1
            // overlaps compute of cb (global-load latency hidden under FMAs)
            #pragma unroll
            for (int cb = 0; cb < NCB; ++cb) {
                __syncthreads();   // staged writes of buf[cb&1] visible; reads of buf[(cb+1)&1] done
                if (cb + 1 < NCB) {
                    if (t < 136) stage((cb + 1) & 1, cb + 1);
                }
                // ---- compute: this thread's c = cb*16 + s ----
                const float* stc = &lds[(cb & 1) * STG];
                float fb[16];
                #pragma unroll
                for (int q = 0; q < 4; ++q)
                    *(float4*)&fb[q * 4] = *(const float4*)&stc[s * F2ST + p0 + q * 4];
                #pragma unroll
                for (int k = 0; k < 8; ++k) {
                    #pragma unroll
                    for (int dw = 0; dw < 9; ++dw)
                        acc[k * 9 + dw] += fa_all[cb * 8 + k] * fb[k + dw];
                }
            }
        }

        // ---- reduce over 16 c-slots + store; two pixel halves (4 kk rows each) ----
        #pragma unroll
        for (int h2 = 0; h2 < 2; ++h2) {
            __syncthreads();
            #pragma unroll
            for (int kk = 0; kk < 4; ++kk) {
                #pragma unroll
                for (int dw = 0; dw < 9; ++dw)
                    lds[(kk * 9 + dw) * RST + t] = acc[(h2 * 4 + kk) * 9 + dw];
            }
            __syncthreads();
            if (t < 128) {
                const int pair = t >> 1;     // 0..63
                const int g2   = pair >> 2;  // 0..15
                const int kk   = pair & 3;
                const int part = t & 1;
                const int px   = g2 * 8 + h2 * 4 + kk;
                float* outp = out + (((long)(n * HH) + h) * WW + w0 + px) * 81 + dh * 9;
                const int dwlo = part ? 5 : 0;
                const int dwhi = part ? 9 : 5;
                for (int dw = dwlo; dw < dwhi; ++dw) {
                    const float* r = &lds[(kk * 9 + dw) * RST + g2 * 16];
                    float4 a0 = *(const float4*)(r);
                    float4 a1 = *(const float4*)(r + 4);
                    float4 a2 = *(const float4*)(r + 8);
                    float4 a3 = *(const float4*)(r + 12);
                    float sum = (((a0.x + a0.y) + (a0.z + a0.w)) + ((a1.x + a1.y) + (a1.z + a1.w)))
                              + (((a2.x + a2.y) + (a2.z + a2.w)) + ((a3.x + a3.y) + (a3.z + a3.w)));
                    outp[dw] = sum * (1.0f / 128.0f);
                }
            }
        }
    }
}

extern "C" void kernel_launch(void* const* d_in, const int* in_sizes, int n_in,
                              void* d_out, int out_size, void* d_ws, size_t ws_size,
                              hipStream_t stream) {
    const float* f1 = (const float*)d_in[0];
    const float* f2 = (const float*)d_in[1];
    float* out = (float*)d_out;
    dim3 grid(NN * HH * 2);   // 2048 workgroups
    dim3 block(256);
    cost_volume_kernel<<<grid, block, 0, stream>>>(f1, f2, out);
}

// Round 2
// 695.900 us; speedup vs baseline: 2.2597x; 2.2597x over previous
//
#include <hip/hip_runtime.h>

// cost volume: out[n,h,w,9*dh+dw] = (1/128) * sum_c f1[n,h,w,c]*f2[n,h+dh-4,w+dw-4,c]
// N=8 H=128 W=256 C=128, zero-padded f2 borders.

#define NN 8
#define HH 128
#define WW 256
#define CC 128

constexpr int WT    = 64;          // w-tile per workgroup
constexpr int P     = 4;           // pixels per 16-lane group
constexpr int KC    = 16;          // c per staged block
constexpr int F2ST  = 76;          // staged row stride (floats)
constexpr int SLOT  = F2ST * KC;   // 1216 floats per ring slot
constexpr int NSLOT = 4;           // ring slots (stage 2 ahead)

__global__ __launch_bounds__(256, 3)
void cost_volume_kernel(const float* __restrict__ f1,
                        const float* __restrict__ f2,
                        float* __restrict__ out) {
    __shared__ __align__(16) float sbuf[NSLOT * SLOT];   // 19.0 KB f2 staging ring
    __shared__ __align__(16) float obuf[64 * 81];        // 20.25 KB output accumulator

    const int t  = threadIdx.x;
    const int g  = t >> 4;      // 0..15 pixel-group
    const int s  = t & 15;      // 0..15 c-slot
    const int p0 = g * P;       // local pixel base 0..60

    // stager role: 9 lanes of each 32-lane half -> 72 stagers spread over all waves
    const int  l32    = t & 31;
    const bool stager = l32 < 9;
    const int  j72    = (t >> 5) * 9 + l32;   // 0..71
    const int  sxb    = j72 >> 2;             // x-block 0..17 (4 px each, covers 72 x)
    const int  scq    = j72 & 3;              // c-quad 0..3 (4 c each)

    // block swizzle: 4096 = 8 xcd * (4 wt * 16 hs * 8 n); contiguous h-chunk per XCD
    const int b   = blockIdx.x;
    const int xcd = b & 7;
    const int i   = b >> 3;            // 0..511
    const int wt  = i & 3;
    const int h   = (xcd << 4) | ((i >> 2) & 15);
    const int n   = i >> 6;            // 0..7
    const int w0  = wt * WT;

    const float* f1row = f1 + (((long)(n * HH) + h) * WW + w0) * CC;
    const float* f2n   = f2 + ((long)(n * HH)) * WW * CC;

    // ---- f1 tile -> registers, read ONCE from HBM (was 9x re-read) ----
    float fa[32];   // fa[cb*4+k] = f1[w0+p0+k][cb*16+s]
    #pragma unroll
    for (int cb = 0; cb < 8; ++cb)
        #pragma unroll
        for (int k = 0; k < 4; ++k)
            fa[cb * 4 + k] = f1row[(p0 + k) * CC + cb * KC + s];

    auto issue_loads = [&](int dh2, int cb2, float4 R[4]) {
        const int y2 = h + dh2 - 4;
        if ((unsigned)y2 < HH) {
            const float* r = f2n + (long)y2 * WW * CC + cb2 * KC + scq * 4;
            #pragma unroll
            for (int ii = 0; ii < 4; ++ii) {
                const int xg = w0 + sxb * 4 - 4 + ii;
                R[ii] = ((unsigned)xg < WW) ? *(const float4*)(r + (long)xg * CC)
                                            : make_float4(0.f, 0.f, 0.f, 0.f);
            }
        } else {
            #pragma unroll
            for (int ii = 0; ii < 4; ++ii) R[ii] = make_float4(0.f, 0.f, 0.f, 0.f);
        }
    };
    auto write_lds = [&](int slot, const float4 R[4]) {
        float* base = &sbuf[slot * SLOT];
        #pragma unroll
        for (int jj = 0; jj < 4; ++jj) {   // 4x4 register transpose -> f2T[c][x]
            float4 w4;
            w4.x = ((const float*)&R[0])[jj];
            w4.y = ((const float*)&R[1])[jj];
            w4.z = ((const float*)&R[2])[jj];
            w4.w = ((const float*)&R[3])[jj];
            *(float4*)&base[(scq * 4 + jj) * F2ST + sxb * 4] = w4;
        }
    };

    // prologue: stage steps 0,1 (dh=0, cb=0,1)
    if (stager) {
        float4 R[4];
        issue_loads(0, 0, R); write_lds(0, R);
        issue_loads(0, 1, R); write_lds(1, R);
    }

    float acc[36];
    #pragma unroll
    for (int a = 0; a < 36; ++a) acc[a] = 0.f;

    for (int dh = 0; dh < 9; ++dh) {
        const int  y    = h + dh - 4;
        const bool vrow = ((unsigned)y < HH);   // workgroup-uniform

        #pragma unroll
        for (int cb = 0; cb < 8; ++cb) {        // cb compile-time: keeps fa[] in registers
            __syncthreads();                    // slot[cb&3] staged & visible
            // T14 split: issue global loads for step m+2 now, LDS-write after compute
            float4 R[4];
            const int  cb2  = (cb + 2) & 7;
            const int  dh2  = dh + ((cb + 2) >> 3);
            const bool doSt = stager && !(dh == 8 && cb >= 6);
            if (doSt) issue_loads(dh2, cb2, R);

            if (vrow) {
                const float* sb = &sbuf[(cb & 3) * SLOT + s * F2ST + p0];
                float fb[12];
                *(float4*)&fb[0] = *(const float4*)(sb);
                *(float4*)&fb[4] = *(const float4*)(sb + 4);
                *(float4*)&fb[8] = *(const float4*)(sb + 8);
                #pragma unroll
                for (int k = 0; k < 4; ++k)
                    #pragma unroll
                    for (int dw = 0; dw < 9; ++dw)
                        acc[k * 9 + dw] += fa[cb * 4 + k] * fb[k + dw];
            }
            if (doSt) write_lds((cb + 2) & 3, R);   // vmcnt wait lands here, after compute
        }

        // ---- value-split shfl reduction over the 16 c-slots (no LDS, no barriers) ----
        // after masks 8,4: lane class k=(s>>2)&3 holds values V = 9k+i (i=0..8)
        const bool hi8 = (s & 8) != 0;
        float r18[18];
        #pragma unroll
        for (int v = 0; v < 18; ++v) {
            float send = hi8 ? acc[v] : acc[v + 18];
            float mine = hi8 ? acc[v + 18] : acc[v];
            r18[v] = mine + __shfl_xor(send, 8, 64);
        }
        const bool hi4 = (s & 4) != 0;
        float r9[9];
        #pragma unroll
        for (int v = 0; v < 9; ++v) {
            float send = hi4 ? r18[v] : r18[v + 9];
            float mine = hi4 ? r18[v + 9] : r18[v];
            r9[v] = mine + __shfl_xor(send, 4, 64);
        }
        #pragma unroll
        for (int v = 0; v < 9; ++v) {
            r9[v] += __shfl_xor(r9[v], 1, 64);
            r9[v] += __shfl_xor(r9[v], 2, 64);
        }
        const int k  = (s >> 2) & 3;   // pixel within group
        const int jj = s & 3;          // dw-third  (jj==3 idle)
        if (jj < 3) {
            const float o0 = (jj == 1) ? r9[3] : ((jj == 2) ? r9[6] : r9[0]);
            const float o1 = (jj == 1) ? r9[4] : ((jj == 2) ? r9[7] : r9[1]);
            const float o2 = (jj == 1) ? r9[5] : ((jj == 2) ? r9[8] : r9[2]);
            float* ob = &obuf[(p0 + k) * 81 + dh * 9 + jj * 3];
            ob[0] = o0 * (1.f / 128.f);
            ob[1] = o1 * (1.f / 128.f);
            ob[2] = o2 * (1.f / 128.f);
        }
        #pragma unroll
        for (int a = 0; a < 36; ++a) acc[a] = 0.f;
    }

    // ---- flush obuf -> out: one contiguous 20.25 KB region, coalesced float4 ----
    __syncthreads();
    float* outbase = out + (((long)(n * HH) + h) * WW + w0) * 81;
    #pragma unroll
    for (int u = 0; u < 6; ++u) {
        const int idx = u * 256 + t;
        if (idx < 1296)   // 64*81/4
            *(float4*)&outbase[idx * 4] = *(const float4*)&obuf[idx * 4];
    }
}

extern "C" void kernel_launch(void* const* d_in, const int* in_sizes, int n_in,
                              void* d_out, int out_size, void* d_ws, size_t ws_size,
                              hipStream_t stream) {
    const float* f1 = (const float*)d_in[0];
    const float* f2 = (const float*)d_in[1];
    float* out = (float*)d_out;
    dim3 grid(NN * HH * 4);   // 4096 workgroups (WT=64)
    dim3 block(256);
    cost_volume_kernel<<<grid, block, 0, stream>>>(f1, f2, out);
}

// Round 3
// 543.746 us; speedup vs baseline: 2.8920x; 1.2798x over previous
//
#include <hip/hip_runtime.h>

// cost volume: out[n,h,w,9*dh+dw] = (1/128) * sum_c f1[n,h,w,c]*f2[n,h+dh-4,w+dw-4,c]
// N=8 H=128 W=256 C=128, zero-padded f2 borders.
//
// v3: row-paired blocks (R=2 output rows share every staged f2 row and every
// fb LDS read), zero-LDS c-reduction via DPP (masks 8,7,2,1 = row_ror:8,
// row_half_mirror, quad_perm), f1 re-read from L2 with immediate-offset loads,
// scratch-free staging temps (struct by reference), direct global stores.

#define NN 8
#define HH 128
#define WW 256
#define CC 128

constexpr int WT    = 64;          // w-tile per workgroup
constexpr int F2ST  = 76;          // staged row stride (floats); 72 used + pad
constexpr int SLOT  = 16 * F2ST;   // 1216 floats per ring slot (16 c-rows)
constexpr int NSLOT = 4;           // ring slots (staged 2 steps ahead)
constexpr int NSTEP = 80;          // 10 f2 rows * 8 c-blocks

// DPP lane shuffle, ctrl immediate. bound_ctrl=1, full row/bank masks.
template<int CTRL>
__device__ __forceinline__ float dshuf(float x) {
    return __int_as_float(__builtin_amdgcn_update_dpp(
        0, __float_as_int(x), CTRL, 0xF, 0xF, true));
}
// xor-1 = quad_perm[1,0,3,2]=0xB1 ; xor-2 = quad_perm[2,3,0,1]=0x4E
// xor-8 = row_ror:8 = 0x128     ; xor-7 = row_half_mirror = 0x141
// group <8,7,2,1> spans all 16 lanes of the c-split.

struct R4 { float4 a, b, c, d; };   // named members: no array decay, stays in VGPRs

// value-split reduce of acc[36] (4 px * 9 dw, partial over this lane's c)
// across the 16 c-slot lanes, then store 9 outputs for pixel class (s3,s2).
__device__ __forceinline__ void reduce_store(const float (&acc)[36], float* outp,
                                             int jj, bool s3, bool s2) {
    float r18[18];
    #pragma unroll
    for (int v = 0; v < 18; ++v) {            // stage mask 8, predicate lane-bit 3
        const float send = s3 ? acc[v] : acc[v + 18];
        const float mine = s3 ? acc[v + 18] : acc[v];
        r18[v] = mine + dshuf<0x128>(send);
    }
    float r9[9];
    #pragma unroll
    for (int v = 0; v < 9; ++v) {             // stage mask 7, predicate lane-bit 2
        const float send = s2 ? r18[v] : r18[v + 9];
        const float mine = s2 ? r18[v + 9] : r18[v];
        r9[v] = mine + dshuf<0x141>(send);
    }
    #pragma unroll
    for (int v = 0; v < 9; ++v) {             // butterfly masks 2, 1
        r9[v] += dshuf<0x4E>(r9[v]);
        r9[v] += dshuf<0xB1>(r9[v]);
    }
    if (jj < 3) {                              // 3 of 4 redundant lanes store 3 dw each
        const float o0 = (jj == 1) ? r9[3] : ((jj == 2) ? r9[6] : r9[0]);
        const float o1 = (jj == 1) ? r9[4] : ((jj == 2) ? r9[7] : r9[1]);
        const float o2 = (jj == 1) ? r9[5] : ((jj == 2) ? r9[8] : r9[2]);
        outp[jj * 3 + 0] = o0 * (1.f / 128.f);
        outp[jj * 3 + 1] = o1 * (1.f / 128.f);
        outp[jj * 3 + 2] = o2 * (1.f / 128.f);
    }
}

__global__ __launch_bounds__(256, 3)
void cost_volume_kernel(const float* __restrict__ f1,
                        const float* __restrict__ f2,
                        float* __restrict__ out) {
    __shared__ __align__(16) float sbuf[NSLOT * SLOT];   // 19.0 KB only

    const int t  = threadIdx.x;
    const int g  = t >> 4;      // 0..15 pixel-group (4 px each)
    const int s  = t & 15;      // 0..15 c-slot
    const int p0 = g * 4;

    // stager role: 9 lanes per 32 -> 72 stagers spread over all 4 waves
    const int  l32    = t & 31;
    const bool stager = l32 < 9;
    const int  j72    = (t >> 5) * 9 + l32;   // 0..71
    const int  sxb    = j72 >> 2;             // x-block 0..17
    const int  scq    = j72 & 3;              // c-quad 0..3

    // swizzle: 2048 blocks = 8 xcd * (8 n * (8 hp * 4 wt)); n outermost per XCD
    const int b   = blockIdx.x;
    const int xcd = b & 7;
    const int i   = b >> 3;            // 0..255
    const int n   = i >> 5;            // 0..7
    const int mid = i & 31;
    const int w0  = (mid & 3) * WT;
    const int h   = (xcd * 8 + (mid >> 2)) * 2;   // even row of the pair

    const float* f2n  = f2 + (long)n * HH * WW * CC;
    const float* f1b0 = f1 + (((long)(n * HH) + h) * WW + w0 + p0) * CC + s;
    const float* f1b1 = f1b0 + (long)WW * CC;

    // output lane mapping: pixel class from lane bits 3,2; dw-third from bits 1,0
    const int opix = g * 4 + 2 * ((s >> 3) & 1) + ((s >> 2) & 1);
    const int jj   = s & 3;
    float* ob0 = out + (((long)(n * HH) + h) * WW + w0 + opix) * 81;
    float* ob1 = ob0 + (long)WW * 81;

    auto issue_loads = [&](int m2, R4& R) {
        const int y2 = h - 4 + (m2 >> 3);
        R.a = R.b = R.c = R.d = make_float4(0.f, 0.f, 0.f, 0.f);
        if ((unsigned)y2 < HH) {
            const float* r = f2n + (long)y2 * WW * CC + (m2 & 7) * 16 + scq * 4;
            const int xb = w0 + sxb * 4 - 4;
            if ((unsigned)(xb + 0) < WW) R.a = *(const float4*)(r + (long)(xb + 0) * CC);
            if ((unsigned)(xb + 1) < WW) R.b = *(const float4*)(r + (long)(xb + 1) * CC);
            if ((unsigned)(xb + 2) < WW) R.c = *(const float4*)(r + (long)(xb + 2) * CC);
            if ((unsigned)(xb + 3) < WW) R.d = *(const float4*)(r + (long)(xb + 3) * CC);
        }
    };
    auto write_lds = [&](int m2, const R4& R) {
        float* dst = &sbuf[(m2 & 3) * SLOT + sxb * 4];   // 4x4 register transpose
        float4 w;
        w = make_float4(R.a.x, R.b.x, R.c.x, R.d.x); *(float4*)&dst[(scq * 4 + 0) * F2ST] = w;
        w = make_float4(R.a.y, R.b.y, R.c.y, R.d.y); *(float4*)&dst[(scq * 4 + 1) * F2ST] = w;
        w = make_float4(R.a.z, R.b.z, R.c.z, R.d.z); *(float4*)&dst[(scq * 4 + 2) * F2ST] = w;
        w = make_float4(R.a.w, R.b.w, R.c.w, R.d.w); *(float4*)&dst[(scq * 4 + 3) * F2ST] = w;
    };

    // prologue: stage steps 0,1
    if (stager) {
        R4 R;
        issue_loads(0, R); write_lds(0, R);
        issue_loads(1, R); write_lds(1, R);
    }

    float acc0[36], acc1[36];
    #pragma unroll
    for (int a2 = 0; a2 < 36; ++a2) { acc0[a2] = 0.f; acc1[a2] = 0.f; }

    for (int m = 0; m < NSTEP; ++m) {
        __syncthreads();                       // slot m&3 staged & visible
        const int yi = m >> 3;                 // f2 row index 0..9 (y = h-4+yi)

        R4 R;                                  // T14: issue early, LDS-write late
        const bool doSt = stager && (m + 2 < NSTEP);
        if (doSt) issue_loads(m + 2, R);

        // fa from L2-resident f1; k*CC*4 + cb*64 fold to immediate offsets
        const float* p0f = f1b0 + (m & 7) * 16;
        const float* p1f = f1b1 + (m & 7) * 16;
        float fa0[4], fa1[4];
        #pragma unroll
        for (int k = 0; k < 4; ++k) { fa0[k] = p0f[k * CC]; fa1[k] = p1f[k * CC]; }

        const float* sb = &sbuf[(m & 3) * SLOT + s * F2ST + p0];
        float fb[12];
        *(float4*)&fb[0] = *(const float4*)(sb);
        *(float4*)&fb[4] = *(const float4*)(sb + 4);
        *(float4*)&fb[8] = *(const float4*)(sb + 8);

        if (yi != 9) {                         // row h: dh = yi (0..8)
            #pragma unroll
            for (int k = 0; k < 4; ++k)
                #pragma unroll
                for (int dw = 0; dw < 9; ++dw)
                    acc0[k * 9 + dw] += fa0[k] * fb[k + dw];
        }
        if (yi != 0) {                         // row h+1: dh = yi-1 (0..8)
            #pragma unroll
            for (int k = 0; k < 4; ++k)
                #pragma unroll
                for (int dw = 0; dw < 9; ++dw)
                    acc1[k * 9 + dw] += fa1[k] * fb[k + dw];
        }

        if (doSt) write_lds(m + 2, R);         // vmcnt wait lands after compute

        if ((m & 7) == 7) {                    // c-blocks done for this f2 row
            const bool s3 = (s & 8) != 0, s2 = (s & 4) != 0;
            if (yi <= 8) reduce_store(acc0, ob0 + (long)yi * 9, jj, s3, s2);
            if (yi >= 1) reduce_store(acc1, ob1 + (long)(yi - 1) * 9, jj, s3, s2);
            #pragma unroll
            for (int a2 = 0; a2 < 36; ++a2) { acc0[a2] = 0.f; acc1[a2] = 0.f; }
        }
    }
}

extern "C" void kernel_launch(void* const* d_in, const int* in_sizes, int n_in,
                              void* d_out, int out_size, void* d_ws, size_t ws_size,
                              hipStream_t stream) {
    const float* f1 = (const float*)d_in[0];
    const float* f2 = (const float*)d_in[1];
    float* out = (float*)d_out;
    dim3 grid(NN * (HH / 2) * (WW / WT));   // 2048 workgroups
    dim3 block(256);
    cost_volume_kernel<<<grid, block, 0, stream>>>(f1, f2, out);
}